// Round 1
// 400.336 us; speedup vs baseline: 1.2174x; 1.2174x over previous
//
#include <hip/hip_runtime.h>

#define HW 512
#define G 64

__device__ __forceinline__ int clampi(int x, int lo, int hi) {
    return min(max(x, lo), hi);
}

// 1D grid, 1344 blocks x 256 threads. Heaviest first:
// blocks [0,768):     s=2 (x4 scale), 4 slices/(b,c), 16 out rows each
// blocks [768,1152):  s=1 (x2 scale), 2 slices/(b,c), 32 out rows each
// blocks [1152,1344): s=0 (copy),     1 block/(b,c)
//
// All global loads are UNCONDITIONAL (clamped addresses); out-of-bounds
// handling is folded into the tap weights. This keeps each pass a single
// basic block so the compiler can batch loads (deep vmcnt pipelining)
// instead of serializing one memory round-trip per tap.
//
// Branchless antialias taps (verified equal to the table form):
//  s=1: base=2o-1, wt={1,3,3,1},        inv = (o==0||o==63) ? 1/7  : 1/8
//  s=2: base=4o-2, wt={1,3,5,7,7,5,3,1},inv = (o==0||o==63) ? 1/28 : 1/32
//  tap dropped (w=0) iff patch index out of [0,N); value zero iff image
//  row/col out of [0,512) -- both folded into w.
__global__ __launch_bounds__(256) void glimpse_kernel(
    const float* __restrict__ img0,
    const float* __restrict__ img2,
    const float* __restrict__ img4,
    const float* __restrict__ loc,
    float* __restrict__ out)
{
    __shared__ float v[4096];  // 16 KB: s1 -> v[32][128], s2 -> v[16][256]

    const int t = threadIdx.x;
    const int blk = blockIdx.x;
    int s, bc, slice = 0;
    if (blk < 768)       { s = 2; bc = blk >> 2; slice = blk & 3; }
    else if (blk < 1152) { s = 1; bc = (blk - 768) >> 1; slice = (blk - 768) & 1; }
    else                 { s = 0; bc = blk - 1152; }
    const int b = bc / 3;
    const int c = bc - 3 * b;

    const float lx = loc[2 * b];
    const float ly = loc[2 * b + 1];
    const int stx = (int)(0.5f * ((lx + 1.0f) * 511.0f));
    const int sty = (int)(0.5f * ((ly + 1.0f) * 511.0f));

    float* outp = out + ((size_t)(b * 3 + s) * 3 + c) * (G * G);

    if (s == 0) {
        const float* img = img0 + (size_t)bc * (HW * HW);
        #pragma unroll
        for (int i = 0; i < 16; i++) {
            int n = i * 256 + t;
            int oy = n >> 6, ox = n & 63;
            int gy = sty + oy - 32, gx = stx + ox - 32;
            int gyc = clampi(gy, 0, HW - 1);
            int gxc = clampi(gx, 0, HW - 1);
            float val = img[gyc * HW + gxc];          // unconditional
            outp[n] = (gy == gyc && gx == gxc) ? val : 0.0f;
        }
        return;
    }

    if (s == 1) {
        const float* img = img2 + (size_t)bc * (HW * HW);
        const int oy0 = slice * 32;
        const int col = t & 127;       // fixed per thread, lanes -> consecutive cols
        const int th  = t >> 7;        // 0 or 1
        const int gx  = stx - 64 + col;
        const int gxc = clampi(gx, 0, HW - 1);
        const float xv = (gx == gxc) ? 1.0f : 0.0f;
        // Pass 1: vertical 4-tap, global (coalesced, branchless) -> v[r][col]
        #pragma unroll 8
        for (int i = 0; i < 16; i++) {
            int r  = 2 * i + th;       // 0..31
            int oy = oy0 + r;
            float inv = (oy == 0 || oy == 63) ? (1.0f / 7.0f) : 0.125f;
            int base = 2 * oy - 1;
            float acc = 0.0f;
            #pragma unroll
            for (int k = 0; k < 4; k++) {
                const float wt = (k == 0 || k == 3) ? 1.0f : 3.0f;
                int ii  = base + k;
                int iic = clampi(ii, 0, 127);
                int gy  = sty - 64 + iic;
                int gyc = clampi(gy, 0, HW - 1);
                float w = (ii == iic && gy == gyc) ? wt * inv : 0.0f;
                acc += w * img[gyc * HW + gxc];       // unconditional
            }
            v[r * 128 + col] = acc * xv;
        }
        __syncthreads();
        // Pass 2: horizontal 4-tap from LDS, coalesced store
        #pragma unroll
        for (int i = 0; i < 8; i++) {
            int m  = i * 256 + t;
            int ox = m & 63;
            int r  = m >> 6;           // 0..31
            float inv = (ox == 0 || ox == 63) ? (1.0f / 7.0f) : 0.125f;
            int base = 2 * ox - 1;
            float acc = 0.0f;
            #pragma unroll
            for (int k = 0; k < 4; k++) {
                const float wt = (k == 0 || k == 3) ? 1.0f : 3.0f;
                int ii  = base + k;
                int iic = clampi(ii, 0, 127);
                float w = (ii == iic) ? wt * inv : 0.0f;
                acc += w * v[r * 128 + iic];
            }
            outp[(size_t)(oy0 + r) * G + ox] = acc;
        }
        return;
    }

    // s == 2
    {
        const float* img = img4 + (size_t)bc * (HW * HW);
        const int oy0 = slice * 16;
        const int col = t;             // 256 threads = 256 cols
        const int gx  = stx - 128 + col;
        const int gxc = clampi(gx, 0, HW - 1);
        const float xv = (gx == gxc) ? 1.0f : 0.0f;
        const float WT[8] = {1.f, 3.f, 5.f, 7.f, 7.f, 5.f, 3.f, 1.f};
        // Pass 1: vertical 8-tap, global (coalesced, branchless) -> v[i][col]
        #pragma unroll 8
        for (int i = 0; i < 16; i++) {
            int oy = oy0 + i;
            float inv = (oy == 0 || oy == 63) ? (1.0f / 28.0f) : (1.0f / 32.0f);
            int base = 4 * oy - 2;
            float acc = 0.0f;
            #pragma unroll
            for (int k = 0; k < 8; k++) {
                int ii  = base + k;
                int iic = clampi(ii, 0, 255);
                int gy  = sty - 128 + iic;
                int gyc = clampi(gy, 0, HW - 1);
                float w = (ii == iic && gy == gyc) ? WT[k] * inv : 0.0f;
                acc += w * img[gyc * HW + gxc];       // unconditional
            }
            v[i * 256 + col] = acc * xv;
        }
        __syncthreads();
        // Pass 2: horizontal 8-tap from LDS, coalesced store
        #pragma unroll
        for (int i = 0; i < 4; i++) {
            int m  = i * 256 + t;
            int ox = m & 63;
            int r  = m >> 6;           // 0..15
            float inv = (ox == 0 || ox == 63) ? (1.0f / 28.0f) : (1.0f / 32.0f);
            int base = 4 * ox - 2;
            float acc = 0.0f;
            #pragma unroll
            for (int k = 0; k < 8; k++) {
                int ii  = base + k;
                int iic = clampi(ii, 0, 255);
                float w = (ii == iic) ? WT[k] * inv : 0.0f;
                acc += w * v[r * 256 + iic];
            }
            outp[(size_t)(oy0 + r) * G + ox] = acc;
        }
    }
}

extern "C" void kernel_launch(void* const* d_in, const int* in_sizes, int n_in,
                              void* d_out, int out_size, void* d_ws, size_t ws_size,
                              hipStream_t stream) {
    const float* img0 = (const float*)d_in[0];
    const float* img2 = (const float*)d_in[1];
    const float* img4 = (const float*)d_in[2];
    const float* loc  = (const float*)d_in[3];
    float* out = (float*)d_out;

    glimpse_kernel<<<dim3(1344), dim3(256), 0, stream>>>(img0, img2, img4, loc, out);
}